// Round 1
// baseline (440.924 us; speedup 1.0000x reference)
//
#include <hip/hip_runtime.h>
#include <hip/hip_cooperative_groups.h>

namespace cg = cooperative_groups;

#define DD 128         // EMBED_DIM
#define CAP 32         // per-row slot capacity (overflow handled exactly)
#define OVF_MAX 4096   // overflow list capacity (int4 entries)
#define EPB 2048       // max edges per phase-1 chunk
#define BSHIFT 10      // bucket = row >> 10 (1024 rows/bucket)
#define NBKT_MAX 64
#define BCAP 24576     // bucket capacity (lambda~16.3K, +64 sigma)
#define WTS 136

typedef __attribute__((ext_vector_type(8))) short short8;  // 8 bf16 (4 VGPRs)
typedef __attribute__((ext_vector_type(4))) float f32x4;   // MFMA C/D

static __device__ __forceinline__ unsigned pack_bf16_2(float lo, float hi) {
  return __builtin_amdgcn_perm(__float_as_uint(hi) + 0x8000u,
                               __float_as_uint(lo) + 0x8000u, 0x07060302u);
}
static __device__ __forceinline__ unsigned short f2bf(float f) {
  return (unsigned short)((__float_as_uint(f) + 0x8000u) >> 16);
}
static __device__ __forceinline__ float bf2f(unsigned short h) {
  return __uint_as_float((unsigned)h << 16);
}

// ---------------------------------------------------------------------------
// Fused cooperative kernel. grid = nbkt + gemmBlocks (<=512, 2 blocks/CU
// co-residency guaranteed by __launch_bounds__(256,2) + 34.8KB LDS).
// Phase 1: all blocks bucket-scatter edges (chunked; contiguous runs per
//          bucket -> merged line writebacks, single XCD per run).
// Phase 2: blocks [0,nbkt) per-bucket placement into spair/counts;
//          blocks [nbkt,..) MFMA GEMM (builds bf16 W^T tile in LDS directly
//          from W -- no Wtg global round-trip, no p1 transpose dependency).
// Phase 3: all blocks grid-stride accumulate (1 wave/row, 16-deep gather
//          batches to keep 16 loads in flight at the reduced 8 waves/CU
//          occupancy of the fused kernel).
// ---------------------------------------------------------------------------
__global__ __launch_bounds__(256, 2) void fused_all(
    const float* __restrict__ U, const float* __restrict__ W,
    const int* __restrict__ rows, const int* __restrict__ cols,
    const float* __restrict__ vals, int* __restrict__ binctr,
    int2* __restrict__ bucket, int* __restrict__ ovf_cnt,
    int4* __restrict__ ovf, int* __restrict__ counts,
    int2* __restrict__ spair, unsigned short* __restrict__ wb,
    float* __restrict__ out, int N, int E, int nbkt) {
  __shared__ union {
    struct {
      int lrow[EPB];          // 8 KB
      int hist[NBKT_MAX];
      int gbase[NBKT_MAX];
      int lcur[NBKT_MAX];
    } p1;
    unsigned short Wt[DD][WTS];  // 34.8 KB (gemm)
    int scnt[1 << BSHIFT];       // 4 KB (placement)
  } sm;

  const int t = threadIdx.x;
  const int nblk = gridDim.x;

  // ---------------- Phase 1: bucket scatter ----------------
  const int epb = max(1, min(EPB, (E + nblk - 1) / nblk));
  const int nch = (E + epb - 1) / epb;
  for (int ch = blockIdx.x; ch < nch; ch += nblk) {
    const int c0 = ch * epb;
    const int n = min(epb, E - c0);

    if (t < NBKT_MAX) { sm.p1.hist[t] = 0; sm.p1.lcur[t] = 0; }
    __syncthreads();

    // Pass A: stage rows, histogram by bucket.
    for (int i = t; i < n; i += 256) {
      const int r = rows[c0 + i];
      sm.p1.lrow[i] = r;
      atomicAdd(&sm.p1.hist[r >> BSHIFT], 1);
    }
    __syncthreads();

    // Reserve contiguous runs in each bucket.
    if (t < nbkt && sm.p1.hist[t] > 0)
      sm.p1.gbase[t] = atomicAdd(&binctr[t], sm.p1.hist[t]);
    __syncthreads();

    // Pass B: place edges into runs (cols/vals re-read coalesced, L2-hot).
    for (int i = t; i < n; i += 256) {
      const int r = sm.p1.lrow[i];
      const int b = r >> BSHIFT;
      const int lpos = atomicAdd(&sm.p1.lcur[b], 1);
      const int idx = sm.p1.gbase[b] + lpos;
      const int col = cols[c0 + i];
      const float v = vals[c0 + i];
      if (idx < BCAP) {
        // pack: bits[31:22] = row&1023, bits[21:0] = col (col < 4M)
        bucket[(size_t)b * BCAP + idx] =
            make_int2(((r & 1023) << 22) | col, __float_as_int(v));
      } else {
        const int o = atomicAdd(ovf_cnt, 1);
        if (o < OVF_MAX) ovf[o] = make_int4(r, col, __float_as_int(v), 0);
      }
    }
    __syncthreads();
  }

  __threadfence();
  cg::this_grid().sync();

  // ---------------- Phase 2: placement || GEMM ----------------
  if ((int)blockIdx.x < nbkt) {
    // ---- placement for bucket b (stores confined to 256 KB window) ----
    const int b = blockIdx.x;
    const int base = b << BSHIFT;
    const int nrows = min(1 << BSHIFT, N - base);
    for (int i = t; i < (1 << BSHIFT); i += 256) sm.scnt[i] = 0;
    __syncthreads();

    const int nb = min(binctr[b], BCAP);
    const int2* __restrict__ bkt = bucket + (size_t)b * BCAP;
    for (int i = t; i < nb; i += 256) {
      const int2 p = bkt[i];
      const int lr = (unsigned)p.x >> 22;
      const int col = p.x & 0x3FFFFF;
      const int slot = atomicAdd(&sm.scnt[lr], 1);
      if (slot < CAP) {
        spair[(size_t)(base + lr) * CAP + slot] = make_int2(col, p.y);
      } else {
        const int o = atomicAdd(ovf_cnt, 1);
        if (o < OVF_MAX) ovf[o] = make_int4(base + lr, col, p.y, 0);
      }
    }
    __syncthreads();
    for (int i = t; i < nrows; i += 256) counts[base + i] = sm.scnt[i];
  } else {
    // ---- GEMM: weighted(bf16) = U @ W, 128 rows/block ----
    const int gb = blockIdx.x - nbkt;
    const int gemmBlocks = (N + 127) >> 7;
    if (gb < gemmBlocks) {
      // Build Wt[n][k] = bf16(W[k][n]) in LDS directly from W (L2-broadcast).
      {
        const int k0 = (t >> 4) * 8;
        const int n0 = (t & 15) * 8;
        float v[8][8];
#pragma unroll
        for (int kk = 0; kk < 8; ++kk) {
          float4 a = *(const float4*)(W + (k0 + kk) * DD + n0);
          float4 b = *(const float4*)(W + (k0 + kk) * DD + n0 + 4);
          v[kk][0] = a.x; v[kk][1] = a.y; v[kk][2] = a.z; v[kk][3] = a.w;
          v[kk][4] = b.x; v[kk][5] = b.y; v[kk][6] = b.z; v[kk][7] = b.w;
        }
#pragma unroll
        for (int nn = 0; nn < 8; ++nn) {
          uint4 d;
          d.x = pack_bf16_2(v[0][nn], v[1][nn]);
          d.y = pack_bf16_2(v[2][nn], v[3][nn]);
          d.z = pack_bf16_2(v[4][nn], v[5][nn]);
          d.w = pack_bf16_2(v[6][nn], v[7][nn]);
          *(uint4*)(&sm.Wt[n0 + nn][k0]) = d;
        }
      }
      __syncthreads();

      const int blk_row0 = gb * 128;
      const int w = t >> 6;
      const int lane = t & 63;
      const int m = lane & 15;
      const int quad = lane >> 4;
      const int row_base = blk_row0 + w * 32;

      short8 afrag[2][4];
#pragma unroll
      for (int s = 0; s < 2; ++s) {
        const int r = min(row_base + s * 16 + m, N - 1);
        const float* up = U + (size_t)r * DD + quad * 8;
#pragma unroll
        for (int c = 0; c < 4; ++c) {
          float4 x = *(const float4*)(up + c * 32);
          float4 y = *(const float4*)(up + c * 32 + 4);
          union { unsigned u[4]; short8 v; } fr;
          fr.u[0] = pack_bf16_2(x.x, x.y);
          fr.u[1] = pack_bf16_2(x.z, x.w);
          fr.u[2] = pack_bf16_2(y.x, y.y);
          fr.u[3] = pack_bf16_2(y.z, y.w);
          afrag[s][c] = fr.v;
        }
      }

      f32x4 acc[2][8];
#pragma unroll
      for (int s = 0; s < 2; ++s)
#pragma unroll
        for (int ct = 0; ct < 8; ++ct) acc[s][ct] = (f32x4){0.f, 0.f, 0.f, 0.f};

#pragma unroll
      for (int c = 0; c < 4; ++c) {
#pragma unroll
        for (int ct = 0; ct < 8; ++ct) {
          short8 bfrag = *(const short8*)&sm.Wt[ct * 16 + m][c * 32 + quad * 8];
          acc[0][ct] = __builtin_amdgcn_mfma_f32_16x16x32_bf16(
              afrag[0][c], bfrag, acc[0][ct], 0, 0, 0);
          acc[1][ct] = __builtin_amdgcn_mfma_f32_16x16x32_bf16(
              afrag[1][c], bfrag, acc[1][ct], 0, 0, 0);
        }
      }

      // Epilogue: C/D layout col=lane&15, row=quad*4+reg  [measured m89/m91].
#pragma unroll
      for (int s = 0; s < 2; ++s) {
        const int rb = row_base + s * 16 + quad * 4;
#pragma unroll
        for (int ct = 0; ct < 8; ++ct) {
#pragma unroll
          for (int reg = 0; reg < 4; ++reg) {
            const int r = rb + reg;
            if (r < N) wb[(size_t)r * DD + ct * 16 + m] = f2bf(acc[s][ct][reg]);
          }
        }
      }
    }
  }

  __threadfence();
  cg::this_grid().sync();

  // ---------------- Phase 3: accumulate (grid-stride, 1 wave/row) ----------
  {
    const int lane = t & 63;
    const int wsel = t >> 6;
    const ushort2* __restrict__ WB2 = (const ushort2*)wb;
    const int ntask = (N + 3) >> 2;
    const int nov = min(*ovf_cnt, OVF_MAX);  // wave-uniform broadcast load

    for (int task = blockIdx.x; task < ntask; task += nblk) {
      const int r = task * 4 + wsel;
      if (r >= N) continue;

      float2 acc = ((const float2*)U)[(size_t)r * 64 + lane];
      const int cnt = min(counts[r], CAP);
      const int2* __restrict__ lst = spair + (size_t)r * CAP;

      int i = 0;
      // 16-deep batch: keep 16 gathers in flight (fused kernel runs at
      // ~8 waves/CU; 8-deep was sized for 32 waves/CU standalone k3).
      for (; i + 16 <= cnt; i += 16) {
        int2 p[16];
#pragma unroll
        for (int j = 0; j < 16; ++j) p[j] = lst[i + j];
        ushort2 a[16];
#pragma unroll
        for (int j = 0; j < 16; ++j) a[j] = WB2[(size_t)p[j].x * 64 + lane];
#pragma unroll
        for (int j = 0; j < 16; ++j) {
          const float v = __int_as_float(p[j].y);
          acc.x = fmaf(v, bf2f(a[j].x), acc.x);
          acc.y = fmaf(v, bf2f(a[j].y), acc.y);
        }
      }
      for (; i + 8 <= cnt; i += 8) {
        int2 p[8];
#pragma unroll
        for (int j = 0; j < 8; ++j) p[j] = lst[i + j];
        ushort2 a[8];
#pragma unroll
        for (int j = 0; j < 8; ++j) a[j] = WB2[(size_t)p[j].x * 64 + lane];
#pragma unroll
        for (int j = 0; j < 8; ++j) {
          const float v = __int_as_float(p[j].y);
          acc.x = fmaf(v, bf2f(a[j].x), acc.x);
          acc.y = fmaf(v, bf2f(a[j].y), acc.y);
        }
      }
      for (; i + 2 <= cnt; i += 2) {
        const int2 p0 = lst[i];
        const int2 p1 = lst[i + 1];
        const ushort2 a0 = WB2[(size_t)p0.x * 64 + lane];
        const ushort2 a1 = WB2[(size_t)p1.x * 64 + lane];
        const float v0 = __int_as_float(p0.y);
        const float v1 = __int_as_float(p1.y);
        acc.x = fmaf(v0, bf2f(a0.x), acc.x);
        acc.y = fmaf(v0, bf2f(a0.y), acc.y);
        acc.x = fmaf(v1, bf2f(a1.x), acc.x);
        acc.y = fmaf(v1, bf2f(a1.y), acc.y);
      }
      if (i < cnt) {
        const int2 p0 = lst[i];
        const ushort2 a0 = WB2[(size_t)p0.x * 64 + lane];
        const float v0 = __int_as_float(p0.y);
        acc.x = fmaf(v0, bf2f(a0.x), acc.x);
        acc.y = fmaf(v0, bf2f(a0.y), acc.y);
      }

      if (nov > 0) {  // normally never taken
        for (int o = 0; o < nov; ++o) {
          const int4 e = ovf[o];
          if (e.x == r) {
            const float v = __int_as_float(e.z);
            const ushort2 a = WB2[(size_t)e.y * 64 + lane];
            acc.x = fmaf(v, bf2f(a.x), acc.x);
            acc.y = fmaf(v, bf2f(a.y), acc.y);
          }
        }
      }

      ((float2*)out)[(size_t)r * 64 + lane] = acc;
    }
  }
}

// ===========================================================================
// Fallback path (ws too small / grid too large): original 3-kernel pipeline.
// ===========================================================================
__global__ __launch_bounds__(256) void p1_bucket(
    const float* __restrict__ W, unsigned short* __restrict__ Wtg,
    const int* __restrict__ rows, const int* __restrict__ cols,
    const float* __restrict__ vals, int* __restrict__ binctr,
    int2* __restrict__ bucket, int* __restrict__ ovf_cnt,
    int4* __restrict__ ovf, int E, int nbkt) {
  const int t = threadIdx.x;
  if (blockIdx.x == 0) {
    const int k0 = (t >> 4) * 8;
    const int n0 = (t & 15) * 8;
    float v[8][8];
#pragma unroll
    for (int kk = 0; kk < 8; ++kk) {
      float4 a = *(const float4*)(W + (k0 + kk) * DD + n0);
      float4 b = *(const float4*)(W + (k0 + kk) * DD + n0 + 4);
      v[kk][0] = a.x; v[kk][1] = a.y; v[kk][2] = a.z; v[kk][3] = a.w;
      v[kk][4] = b.x; v[kk][5] = b.y; v[kk][6] = b.z; v[kk][7] = b.w;
    }
#pragma unroll
    for (int nn = 0; nn < 8; ++nn) {
      uint4 d;
      d.x = pack_bf16_2(v[0][nn], v[1][nn]);
      d.y = pack_bf16_2(v[2][nn], v[3][nn]);
      d.z = pack_bf16_2(v[4][nn], v[5][nn]);
      d.w = pack_bf16_2(v[6][nn], v[7][nn]);
      *(uint4*)(Wtg + (size_t)(n0 + nn) * DD + k0) = d;
    }
    return;
  }
  // (bucket scatter unused in fallback; E==0 there)
  __shared__ int lrow[EPB];
  __shared__ int hist[NBKT_MAX];
  __shared__ int gbase[NBKT_MAX];
  __shared__ int lcur[NBKT_MAX];
  const int c0 = (blockIdx.x - 1) * EPB;
  const int n = min(EPB, E - c0);
  if (t < NBKT_MAX) { hist[t] = 0; lcur[t] = 0; }
  __syncthreads();
  for (int i = t; i < n; i += 256) {
    const int r = rows[c0 + i];
    lrow[i] = r;
    atomicAdd(&hist[r >> BSHIFT], 1);
  }
  __syncthreads();
  if (t < nbkt && hist[t] > 0) gbase[t] = atomicAdd(&binctr[t], hist[t]);
  __syncthreads();
  for (int i = t; i < n; i += 256) {
    const int r = lrow[i];
    const int b = r >> BSHIFT;
    const int lpos = atomicAdd(&lcur[b], 1);
    const int idx = gbase[b] + lpos;
    const int col = cols[c0 + i];
    const float v = vals[c0 + i];
    if (idx < BCAP) {
      bucket[(size_t)b * BCAP + idx] =
          make_int2(((r & 1023) << 22) | col, __float_as_int(v));
    } else {
      const int o = atomicAdd(ovf_cnt, 1);
      if (o < OVF_MAX) ovf[o] = make_int4(r, col, __float_as_int(v), 0);
    }
  }
}

__global__ __launch_bounds__(256) void p2k2_fused(
    const int* __restrict__ binctr, const int2* __restrict__ bucket,
    int* __restrict__ counts, int2* __restrict__ spair,
    int* __restrict__ ovf_cnt, int4* __restrict__ ovf,
    const float* __restrict__ U, const unsigned short* __restrict__ Wtg,
    unsigned short* __restrict__ wb, float* __restrict__ out, int N,
    int nbkt, int do_copy) {
  __shared__ union {
    unsigned short Wt[DD][WTS];
    int scnt[1 << BSHIFT];
  } sm;
  const int t = threadIdx.x;

  if ((int)blockIdx.x < nbkt) {
    const int b = blockIdx.x;
    const int base = b << BSHIFT;
    const int nrows = min(1 << BSHIFT, N - base);
    for (int i = t; i < (1 << BSHIFT); i += 256) sm.scnt[i] = 0;
    __syncthreads();
    const int nb = min(binctr[b], BCAP);
    const int2* __restrict__ bkt = bucket + (size_t)b * BCAP;
    for (int i = t; i < nb; i += 256) {
      const int2 p = bkt[i];
      const int lr = (unsigned)p.x >> 22;
      const int col = p.x & 0x3FFFFF;
      const int slot = atomicAdd(&sm.scnt[lr], 1);
      if (slot < CAP) {
        spair[(size_t)(base + lr) * CAP + slot] = make_int2(col, p.y);
      } else {
        const int o = atomicAdd(ovf_cnt, 1);
        if (o < OVF_MAX) ovf[o] = make_int4(base + lr, col, p.y, 0);
      }
    }
    __syncthreads();
    for (int i = t; i < nrows; i += 256) counts[base + i] = sm.scnt[i];
    return;
  }

  const int gb = blockIdx.x - nbkt;
#pragma unroll
  for (int i = 0; i < 8; ++i) {
    const int s = t + 256 * i;
    const int nn = s >> 4;
    const int k0 = (s & 15) * 8;
    uint4 d = *(const uint4*)(Wtg + (size_t)nn * DD + k0);
    *(uint4*)(&sm.Wt[nn][k0]) = d;
  }

  const int blk_row0 = gb * 128;
  if (do_copy) {
    const int nrow = min(128, N - blk_row0);
    const float4* U4 = (const float4*)(U + (size_t)blk_row0 * DD);
    float4* O4 = (float4*)(out + (size_t)blk_row0 * DD);
    for (int i = t; i < nrow * 32; i += 256) O4[i] = U4[i];
  }
  __syncthreads();

  const int w = t >> 6;
  const int lane = t & 63;
  const int m = lane & 15;
  const int quad = lane >> 4;
  const int row_base = blk_row0 + w * 32;

  short8 afrag[2][4];
#pragma unroll
  for (int s = 0; s < 2; ++s) {
    const int r = min(row_base + s * 16 + m, N - 1);
    const float* up = U + (size_t)r * DD + quad * 8;
#pragma unroll
    for (int c = 0; c < 4; ++c) {
      float4 x = *(const float4*)(up + c * 32);
      float4 y = *(const float4*)(up + c * 32 + 4);
      union { unsigned u[4]; short8 v; } fr;
      fr.u[0] = pack_bf16_2(x.x, x.y);
      fr.u[1] = pack_bf16_2(x.z, x.w);
      fr.u[2] = pack_bf16_2(y.x, y.y);
      fr.u[3] = pack_bf16_2(y.z, y.w);
      afrag[s][c] = fr.v;
    }
  }

  f32x4 acc[2][8];
#pragma unroll
  for (int s = 0; s < 2; ++s)
#pragma unroll
    for (int ct = 0; ct < 8; ++ct) acc[s][ct] = (f32x4){0.f, 0.f, 0.f, 0.f};

#pragma unroll
  for (int c = 0; c < 4; ++c) {
#pragma unroll
    for (int ct = 0; ct < 8; ++ct) {
      short8 bfrag = *(const short8*)&sm.Wt[ct * 16 + m][c * 32 + quad * 8];
      acc[0][ct] = __builtin_amdgcn_mfma_f32_16x16x32_bf16(
          afrag[0][c], bfrag, acc[0][ct], 0, 0, 0);
      acc[1][ct] = __builtin_amdgcn_mfma_f32_16x16x32_bf16(
          afrag[1][c], bfrag, acc[1][ct], 0, 0, 0);
    }
  }

#pragma unroll
  for (int s = 0; s < 2; ++s) {
    const int rb = row_base + s * 16 + quad * 4;
#pragma unroll
    for (int ct = 0; ct < 8; ++ct) {
#pragma unroll
      for (int reg = 0; reg < 4; ++reg) {
        const int r = rb + reg;
        if (r < N) wb[(size_t)r * DD + ct * 16 + m] = f2bf(acc[s][ct][reg]);
      }
    }
  }
}

__global__ __launch_bounds__(256) void scatter_kernel(
    const int* __restrict__ rows, const int* __restrict__ cols,
    const float* __restrict__ vals, const unsigned short* __restrict__ wb,
    float* __restrict__ out, int E) {
  const int tid = blockIdx.x * 256 + threadIdx.x;
  const int e = tid >> 6;
  if (e >= E) return;
  const int lane = tid & 63;

  const int row = rows[e];
  const int col = cols[e];
  const float v = vals[e];

  const ushort2 w = ((const ushort2*)wb)[(size_t)col * 64 + lane];
  float* dst = out + (size_t)row * DD + lane * 2;
  unsafeAtomicAdd(dst, v * bf2f(w.x));
  unsafeAtomicAdd(dst + 1, v * bf2f(w.y));
}

static inline size_t align_up(size_t x, size_t a) { return (x + a - 1) & ~(a - 1); }

extern "C" void kernel_launch(void* const* d_in, const int* in_sizes, int n_in,
                              void* d_out, int out_size, void* d_ws, size_t ws_size,
                              hipStream_t stream) {
  const float* U = (const float*)d_in[0];     // [N, 128]
  const float* W = (const float*)d_in[1];     // [128, 128]
  const int* rows = (const int*)d_in[2];      // [E]
  const int* cols = (const int*)d_in[3];      // [E]
  const float* vals = (const float*)d_in[4];  // [E]
  float* out = (float*)d_out;                 // [N, 128]

  const int N = in_sizes[0] / DD;
  const int E = in_sizes[2];
  const int gemmBlocks = (N + 127) / 128;
  const int nbkt = (N + (1 << BSHIFT) - 1) >> BSHIFT;  // 49 for N=50000
  const int grid = nbkt + gemmBlocks;                  // 440 for N=50000

  // Workspace layout (16 B aligned segments)
  char* ws = (char*)d_ws;
  size_t off = 0;
  unsigned short* wb = (unsigned short*)(ws + off);
  off = align_up(off + (size_t)N * DD * sizeof(unsigned short), 16);
  unsigned short* Wtg = (unsigned short*)(ws + off);  // fallback only
  off = align_up(off + (size_t)DD * DD * sizeof(unsigned short), 16);
  int* counts = (int*)(ws + off);
  off = align_up(off + (size_t)N * sizeof(int), 16);
  int* binctr = (int*)(ws + off);  // NBKT_MAX bins + ovf counter, zeroed together
  int* ovf_cnt = binctr + NBKT_MAX;
  off = align_up(off + (NBKT_MAX + 4) * sizeof(int), 16);
  int4* ovf = (int4*)(ws + off);
  off = align_up(off + (size_t)OVF_MAX * sizeof(int4), 16);
  int2* bucket = (int2*)(ws + off);
  off = align_up(off + (size_t)nbkt * BCAP * sizeof(int2), 16);
  int2* spair = (int2*)(ws + off);
  off = align_up(off + (size_t)N * CAP * sizeof(int2), 16);
  // Co-residency bound: __launch_bounds__(256,2) + 34.8KB LDS -> >=2 blk/CU.
  const bool fast_ok =
      (off <= ws_size) && (nbkt <= NBKT_MAX) && (grid <= 512) && (E > 0);

  if (fast_ok) {
    hipMemsetAsync(binctr, 0, (NBKT_MAX + 1) * sizeof(int), stream);  // 260 B
    int N_ = N, E_ = E, nbkt_ = nbkt;
    void* args[] = {(void*)&U,      (void*)&W,      (void*)&rows,
                    (void*)&cols,   (void*)&vals,   (void*)&binctr,
                    (void*)&bucket, (void*)&ovf_cnt,(void*)&ovf,
                    (void*)&counts, (void*)&spair,  (void*)&wb,
                    (void*)&out,    (void*)&N_,     (void*)&E_,
                    (void*)&nbkt_};
    hipLaunchCooperativeKernel((const void*)fused_all, dim3(grid), dim3(256),
                               args, 0, stream);
  } else {
    // Fallback: transpose only, gemm w/ residual copy, atomic scatter.
    p1_bucket<<<1, 256, 0, stream>>>(W, Wtg, rows, cols, vals, (int*)Wtg,
                                     (int2*)Wtg, (int*)Wtg, (int4*)Wtg, 0, 0);
    p2k2_fused<<<gemmBlocks, 256, 0, stream>>>(
        (const int*)Wtg, (const int2*)Wtg, (int*)Wtg, (int2*)Wtg, (int*)Wtg,
        (int4*)Wtg, U, Wtg, wb, out, N, 0, 1);
    const long long total = (long long)E * 64;
    scatter_kernel<<<(int)((total + 255) / 256), 256, 0, stream>>>(
        rows, cols, vals, wb, out, E);
  }
}

// Round 2
// 161.872 us; speedup vs baseline: 2.7239x; 2.7239x over previous
//
#include <hip/hip_runtime.h>

#define DD 128         // EMBED_DIM
#define CAP 32         // per-row slot capacity (overflow handled exactly)
#define OVF_MAX 4096   // overflow list capacity (int4 entries)
#define EPB 2048       // edges per p1 chunk
#define BSHIFT 10      // bucket = row >> 10 (1024 rows/bucket)
#define NBKT_MAX 64
#define BCAP 24576     // bucket capacity (lambda~16.3K, +64 sigma)

typedef __attribute__((ext_vector_type(8))) short short8;           // 8 bf16
typedef __attribute__((ext_vector_type(8))) unsigned short u16x8;   // 8 bf16
typedef __attribute__((ext_vector_type(4))) float f32x4;            // MFMA C/D

static __device__ __forceinline__ unsigned pack_bf16_2(float lo, float hi) {
  return __builtin_amdgcn_perm(__float_as_uint(hi) + 0x8000u,
                               __float_as_uint(lo) + 0x8000u, 0x07060302u);
}
static __device__ __forceinline__ unsigned short f2bf(float f) {
  return (unsigned short)((__float_as_uint(f) + 0x8000u) >> 16);
}
static __device__ __forceinline__ float bf2f(unsigned short h) {
  return __uint_as_float((unsigned)h << 16);
}

// ---------------------------------------------------------------------------
// p1: block 0 -> Wt[n][k] = bf16(W[k][n]) transpose. Blocks 1..: bucket
// scatter. Per 2048-edge chunk: LDS histogram by row>>10, one global
// atomicAdd per (block,bucket) reserves a contiguous run, edges written as
// dense 8 B runs (~40 consecutive -> full-line writebacks, single XCD).
// ---------------------------------------------------------------------------
__global__ __launch_bounds__(256) void p1_bucket(
    const float* __restrict__ W, unsigned short* __restrict__ Wtg,
    const int* __restrict__ rows, const int* __restrict__ cols,
    const float* __restrict__ vals, int* __restrict__ binctr,
    int2* __restrict__ bucket, int* __restrict__ ovf_cnt,
    int4* __restrict__ ovf, int E, int nbkt) {
  const int t = threadIdx.x;
  if (blockIdx.x == 0) {
    const int k0 = (t >> 4) * 8;
    const int n0 = (t & 15) * 8;
    float v[8][8];
#pragma unroll
    for (int kk = 0; kk < 8; ++kk) {
      float4 a = *(const float4*)(W + (k0 + kk) * DD + n0);
      float4 b = *(const float4*)(W + (k0 + kk) * DD + n0 + 4);
      v[kk][0] = a.x; v[kk][1] = a.y; v[kk][2] = a.z; v[kk][3] = a.w;
      v[kk][4] = b.x; v[kk][5] = b.y; v[kk][6] = b.z; v[kk][7] = b.w;
    }
#pragma unroll
    for (int nn = 0; nn < 8; ++nn) {
      uint4 d;
      d.x = pack_bf16_2(v[0][nn], v[1][nn]);
      d.y = pack_bf16_2(v[2][nn], v[3][nn]);
      d.z = pack_bf16_2(v[4][nn], v[5][nn]);
      d.w = pack_bf16_2(v[6][nn], v[7][nn]);
      *(uint4*)(Wtg + (size_t)(n0 + nn) * DD + k0) = d;
    }
    return;
  }

  __shared__ int lrow[EPB];            // 8 KB
  __shared__ int hist[NBKT_MAX];
  __shared__ int gbase[NBKT_MAX];
  __shared__ int lcur[NBKT_MAX];

  const int c0 = (blockIdx.x - 1) * EPB;
  const int n = min(EPB, E - c0);

  if (t < NBKT_MAX) { hist[t] = 0; lcur[t] = 0; }
  __syncthreads();

  // Pass A: stage rows, histogram by bucket.
  for (int i = t; i < n; i += 256) {
    const int r = rows[c0 + i];
    lrow[i] = r;
    atomicAdd(&hist[r >> BSHIFT], 1);
  }
  __syncthreads();

  // Reserve contiguous runs in each bucket.
  if (t < nbkt && hist[t] > 0) gbase[t] = atomicAdd(&binctr[t], hist[t]);
  __syncthreads();

  // Pass B: place edges into runs (cols/vals re-read coalesced, L2-hot).
  for (int i = t; i < n; i += 256) {
    const int r = lrow[i];
    const int b = r >> BSHIFT;
    const int lpos = atomicAdd(&lcur[b], 1);
    const int idx = gbase[b] + lpos;
    const int col = cols[c0 + i];
    const float v = vals[c0 + i];
    if (idx < BCAP) {
      // pack: bits[31:22] = row&1023, bits[21:0] = col (col < 4M)
      bucket[(size_t)b * BCAP + idx] =
          make_int2(((r & 1023) << 22) | col, __float_as_int(v));
    } else {
      const int o = atomicAdd(ovf_cnt, 1);
      if (o < OVF_MAX) ovf[o] = make_int4(r, col, __float_as_int(v), 0);
    }
  }
}

// ---------------------------------------------------------------------------
// p2k2 fused: blocks [0,nbkt) -> per-bucket placement (LDS slot counters,
// stores confined to a 256 KB block-private window -> full L2 merging; also
// writes counts[] so no big memset). Blocks [nbkt,..) -> MFMA GEMM.
// ---------------------------------------------------------------------------
#define WTS 136
__global__ __launch_bounds__(256) void p2k2_fused(
    const int* __restrict__ binctr, const int2* __restrict__ bucket,
    int* __restrict__ counts, int2* __restrict__ spair,
    int* __restrict__ ovf_cnt, int4* __restrict__ ovf,
    const float* __restrict__ U, const unsigned short* __restrict__ Wtg,
    unsigned short* __restrict__ wb, float* __restrict__ out, int N,
    int nbkt, int do_copy) {
  __shared__ union {
    unsigned short Wt[DD][WTS];  // 34.8 KB (gemm)
    int scnt[1 << BSHIFT];       // 4 KB (placement)
  } sm;
  const int t = threadIdx.x;

  if ((int)blockIdx.x < nbkt) {
    // ---- placement for bucket b ----
    const int b = blockIdx.x;
    const int base = b << BSHIFT;
    const int nrows = min(1 << BSHIFT, N - base);
    for (int i = t; i < (1 << BSHIFT); i += 256) sm.scnt[i] = 0;
    __syncthreads();

    const int nb = min(binctr[b], BCAP);
    const int2* __restrict__ bkt = bucket + (size_t)b * BCAP;
    for (int i = t; i < nb; i += 256) {
      const int2 p = bkt[i];
      const int lr = (unsigned)p.x >> 22;
      const int col = p.x & 0x3FFFFF;
      const int slot = atomicAdd(&sm.scnt[lr], 1);
      if (slot < CAP) {
        spair[(size_t)(base + lr) * CAP + slot] = make_int2(col, p.y);
      } else {
        const int o = atomicAdd(ovf_cnt, 1);
        if (o < OVF_MAX) ovf[o] = make_int4(base + lr, col, p.y, 0);
      }
    }
    __syncthreads();
    for (int i = t; i < nrows; i += 256) counts[base + i] = sm.scnt[i];
    return;
  }

  // ---- GEMM: weighted(bf16) = U @ W, 128 rows/block, 4 waves x 32 rows ----
  const int gb = blockIdx.x - nbkt;
#pragma unroll
  for (int i = 0; i < 8; ++i) {
    const int s = t + 256 * i;
    const int nn = s >> 4;
    const int k0 = (s & 15) * 8;
    uint4 d = *(const uint4*)(Wtg + (size_t)nn * DD + k0);
    *(uint4*)(&sm.Wt[nn][k0]) = d;
  }

  const int blk_row0 = gb * 128;
  if (do_copy) {
    const int nrow = min(128, N - blk_row0);
    const float4* U4 = (const float4*)(U + (size_t)blk_row0 * DD);
    float4* O4 = (float4*)(out + (size_t)blk_row0 * DD);
    for (int i = t; i < nrow * 32; i += 256) O4[i] = U4[i];
  }
  __syncthreads();

  const int w = t >> 6;
  const int lane = t & 63;
  const int m = lane & 15;
  const int quad = lane >> 4;
  const int row_base = blk_row0 + w * 32;

  short8 afrag[2][4];
#pragma unroll
  for (int s = 0; s < 2; ++s) {
    const int r = min(row_base + s * 16 + m, N - 1);
    const float* up = U + (size_t)r * DD + quad * 8;
#pragma unroll
    for (int c = 0; c < 4; ++c) {
      float4 x = *(const float4*)(up + c * 32);
      float4 y = *(const float4*)(up + c * 32 + 4);
      union { unsigned u[4]; short8 v; } fr;
      fr.u[0] = pack_bf16_2(x.x, x.y);
      fr.u[1] = pack_bf16_2(x.z, x.w);
      fr.u[2] = pack_bf16_2(y.x, y.y);
      fr.u[3] = pack_bf16_2(y.z, y.w);
      afrag[s][c] = fr.v;
    }
  }

  f32x4 acc[2][8];
#pragma unroll
  for (int s = 0; s < 2; ++s)
#pragma unroll
    for (int ct = 0; ct < 8; ++ct) acc[s][ct] = (f32x4){0.f, 0.f, 0.f, 0.f};

#pragma unroll
  for (int c = 0; c < 4; ++c) {
#pragma unroll
    for (int ct = 0; ct < 8; ++ct) {
      short8 bfrag = *(const short8*)&sm.Wt[ct * 16 + m][c * 32 + quad * 8];
      acc[0][ct] = __builtin_amdgcn_mfma_f32_16x16x32_bf16(
          afrag[0][c], bfrag, acc[0][ct], 0, 0, 0);
      acc[1][ct] = __builtin_amdgcn_mfma_f32_16x16x32_bf16(
          afrag[1][c], bfrag, acc[1][ct], 0, 0, 0);
    }
  }

  // Epilogue: C/D layout col=lane&15, row=quad*4+reg  [measured m89/m91].
#pragma unroll
  for (int s = 0; s < 2; ++s) {
    const int rb = row_base + s * 16 + quad * 4;
#pragma unroll
    for (int ct = 0; ct < 8; ++ct) {
#pragma unroll
      for (int reg = 0; reg < 4; ++reg) {
        const int r = rb + reg;
        if (r < N) wb[(size_t)r * DD + ct * 16 + m] = f2bf(acc[s][ct][reg]);
      }
    }
  }
}

// ---------------------------------------------------------------------------
// k3: accumulate. One wave per output row. NEW gather shape: lane group
// g=lane>>4 owns an edge, slot sl=lane&15 owns 8 dims -> each gather
// instruction fetches 4 edges x 16 B/lane = 1 KB/wave (was 4 B/lane, 256 B).
// 4x fewer VMEM ops, 2x outstanding bytes; wave-uniform trip count via
// masked tail (clamped index, zeroed val). Cross-group shfl_xor reduction.
// ---------------------------------------------------------------------------
__global__ __launch_bounds__(256) void k3_accumulate(
    const int* __restrict__ counts, const int2* __restrict__ spair,
    const unsigned short* __restrict__ wb, const float* __restrict__ U,
    const int* __restrict__ ovf_cnt, const int4* __restrict__ ovf,
    float* __restrict__ out, int N) {
  const int r = blockIdx.x * 4 + (threadIdx.x >> 6);
  if (r >= N) return;
  const int lane = threadIdx.x & 63;
  const int g = lane >> 4;    // edge subgroup 0..3
  const int sl = lane & 15;   // dim slot: dims [8*sl .. 8*sl+7]

  const u16x8* __restrict__ WB8 = (const u16x8*)wb;  // row = 16 x u16x8

  float acc[8];
#pragma unroll
  for (int d = 0; d < 8; ++d) acc[d] = 0.f;

  const int cnt = min(counts[r], CAP);
  const int2* __restrict__ lst = spair + (size_t)r * CAP;

  int i = 0;
  // main: 16 edges / iter, 4 wide gathers issued back-to-back
  for (; i + 16 <= cnt; i += 16) {
    const int2 p0 = lst[i + g];
    const int2 p1 = lst[i + 4 + g];
    const int2 p2 = lst[i + 8 + g];
    const int2 p3 = lst[i + 12 + g];
    const u16x8 a0 = WB8[(size_t)p0.x * 16 + sl];
    const u16x8 a1 = WB8[(size_t)p1.x * 16 + sl];
    const u16x8 a2 = WB8[(size_t)p2.x * 16 + sl];
    const u16x8 a3 = WB8[(size_t)p3.x * 16 + sl];
    const float v0 = __int_as_float(p0.y);
    const float v1 = __int_as_float(p1.y);
    const float v2 = __int_as_float(p2.y);
    const float v3 = __int_as_float(p3.y);
#pragma unroll
    for (int d = 0; d < 8; ++d) {
      acc[d] = fmaf(v0, bf2f((unsigned short)a0[d]), acc[d]);
      acc[d] = fmaf(v1, bf2f((unsigned short)a1[d]), acc[d]);
      acc[d] = fmaf(v2, bf2f((unsigned short)a2[d]), acc[d]);
      acc[d] = fmaf(v3, bf2f((unsigned short)a3[d]), acc[d]);
    }
  }

  const int rem = cnt - i;  // 0..15
  if (rem > 8) {
    // masked 16-edge step (clamped index, zeroed val for j >= cnt)
    const int e0 = i + g, e1 = i + 4 + g, e2 = i + 8 + g, e3 = i + 12 + g;
    const int2 p0 = lst[min(e0, cnt - 1)];
    const int2 p1 = lst[min(e1, cnt - 1)];
    const int2 p2 = lst[min(e2, cnt - 1)];
    const int2 p3 = lst[min(e3, cnt - 1)];
    const u16x8 a0 = WB8[(size_t)p0.x * 16 + sl];
    const u16x8 a1 = WB8[(size_t)p1.x * 16 + sl];
    const u16x8 a2 = WB8[(size_t)p2.x * 16 + sl];
    const u16x8 a3 = WB8[(size_t)p3.x * 16 + sl];
    const float v0 = (e0 < cnt) ? __int_as_float(p0.y) : 0.f;
    const float v1 = (e1 < cnt) ? __int_as_float(p1.y) : 0.f;
    const float v2 = (e2 < cnt) ? __int_as_float(p2.y) : 0.f;
    const float v3 = (e3 < cnt) ? __int_as_float(p3.y) : 0.f;
#pragma unroll
    for (int d = 0; d < 8; ++d) {
      acc[d] = fmaf(v0, bf2f((unsigned short)a0[d]), acc[d]);
      acc[d] = fmaf(v1, bf2f((unsigned short)a1[d]), acc[d]);
      acc[d] = fmaf(v2, bf2f((unsigned short)a2[d]), acc[d]);
      acc[d] = fmaf(v3, bf2f((unsigned short)a3[d]), acc[d]);
    }
  } else if (rem > 0) {
    // masked 8-edge step
    const int e0 = i + g, e1 = i + 4 + g;
    const int2 p0 = lst[min(e0, cnt - 1)];
    const int2 p1 = lst[min(e1, cnt - 1)];
    const u16x8 a0 = WB8[(size_t)p0.x * 16 + sl];
    const u16x8 a1 = WB8[(size_t)p1.x * 16 + sl];
    const float v0 = (e0 < cnt) ? __int_as_float(p0.y) : 0.f;
    const float v1 = (e1 < cnt) ? __int_as_float(p1.y) : 0.f;
#pragma unroll
    for (int d = 0; d < 8; ++d) {
      acc[d] = fmaf(v0, bf2f((unsigned short)a0[d]), acc[d]);
      acc[d] = fmaf(v1, bf2f((unsigned short)a1[d]), acc[d]);
    }
  }

  // reduce the 4 edge-subgroups: lanes {sl, sl+16, sl+32, sl+48} -> sl
#pragma unroll
  for (int d = 0; d < 8; ++d) {
    acc[d] += __shfl_xor(acc[d], 16, 64);
    acc[d] += __shfl_xor(acc[d], 32, 64);
  }

  // overflow entries (normally empty); only the surviving quarter-wave adds
  const int nov = min(*ovf_cnt, OVF_MAX);  // wave-uniform broadcast load
  if (nov > 0 && lane < 16) {
    for (int o = 0; o < nov; ++o) {
      const int4 e = ovf[o];
      if (e.x == r) {
        const float v = __int_as_float(e.z);
        const u16x8 a = WB8[(size_t)e.y * 16 + sl];
#pragma unroll
        for (int d = 0; d < 8; ++d)
          acc[d] = fmaf(v, bf2f((unsigned short)a[d]), acc[d]);
      }
    }
  }

  // residual add + store (quarter-wave, 2x float4 per lane = full 512 B row)
  if (lane < 16) {
    const float* up = U + (size_t)r * DD + sl * 8;
    const float4 u0 = *(const float4*)up;
    const float4 u1 = *(const float4*)(up + 4);
    float4 o0, o1;
    o0.x = acc[0] + u0.x; o0.y = acc[1] + u0.y;
    o0.z = acc[2] + u0.z; o0.w = acc[3] + u0.w;
    o1.x = acc[4] + u1.x; o1.y = acc[5] + u1.y;
    o1.z = acc[6] + u1.z; o1.w = acc[7] + u1.w;
    float* op = out + (size_t)r * DD + sl * 8;
    *(float4*)op = o0;
    *(float4*)(op + 4) = o1;
  }
}

// ---------------------------------------------------------------------------
// Fallback scatter (ws too small): f32 atomics into out (= U, via do_copy).
// ---------------------------------------------------------------------------
__global__ __launch_bounds__(256) void scatter_kernel(
    const int* __restrict__ rows, const int* __restrict__ cols,
    const float* __restrict__ vals, const unsigned short* __restrict__ wb,
    float* __restrict__ out, int E) {
  const int tid = blockIdx.x * 256 + threadIdx.x;
  const int e = tid >> 6;
  if (e >= E) return;
  const int lane = tid & 63;

  const int row = rows[e];
  const int col = cols[e];
  const float v = vals[e];

  const ushort2 w = ((const ushort2*)wb)[(size_t)col * 64 + lane];
  float* dst = out + (size_t)row * DD + lane * 2;
  unsafeAtomicAdd(dst, v * bf2f(w.x));
  unsafeAtomicAdd(dst + 1, v * bf2f(w.y));
}

static inline size_t align_up(size_t x, size_t a) { return (x + a - 1) & ~(a - 1); }

extern "C" void kernel_launch(void* const* d_in, const int* in_sizes, int n_in,
                              void* d_out, int out_size, void* d_ws, size_t ws_size,
                              hipStream_t stream) {
  const float* U = (const float*)d_in[0];     // [N, 128]
  const float* W = (const float*)d_in[1];     // [128, 128]
  const int* rows = (const int*)d_in[2];      // [E]
  const int* cols = (const int*)d_in[3];      // [E]
  const float* vals = (const float*)d_in[4];  // [E]
  float* out = (float*)d_out;                 // [N, 128]

  const int N = in_sizes[0] / DD;
  const int E = in_sizes[2];
  const int gemmBlocks = (N + 127) / 128;
  const int nchunks = (E + EPB - 1) / EPB;
  const int nbkt = (N + (1 << BSHIFT) - 1) >> BSHIFT;  // 49 for N=50000

  // Workspace layout (16 B aligned segments)
  char* ws = (char*)d_ws;
  size_t off = 0;
  unsigned short* wb = (unsigned short*)(ws + off);
  off = align_up(off + (size_t)N * DD * sizeof(unsigned short), 16);
  unsigned short* Wtg = (unsigned short*)(ws + off);
  off = align_up(off + (size_t)DD * DD * sizeof(unsigned short), 16);
  int* counts = (int*)(ws + off);
  off = align_up(off + (size_t)N * sizeof(int), 16);
  int* binctr = (int*)(ws + off);  // NBKT_MAX bins + ovf counter, zeroed together
  int* ovf_cnt = binctr + NBKT_MAX;
  off = align_up(off + (NBKT_MAX + 4) * sizeof(int), 16);
  int4* ovf = (int4*)(ws + off);
  off = align_up(off + (size_t)OVF_MAX * sizeof(int4), 16);
  int2* bucket = (int2*)(ws + off);
  off = align_up(off + (size_t)nbkt * BCAP * sizeof(int2), 16);
  int2* spair = (int2*)(ws + off);
  off = align_up(off + (size_t)N * CAP * sizeof(int2), 16);
  const bool fast_ok = (off <= ws_size) && (nbkt <= NBKT_MAX);

  if (fast_ok) {
    hipMemsetAsync(binctr, 0, (NBKT_MAX + 1) * sizeof(int), stream);  // 260 B
    // p1: transpose (block 0) || bucket scatter (blocks 1..)
    p1_bucket<<<1 + nchunks, 256, 0, stream>>>(
        W, Wtg, rows, cols, vals, binctr, bucket, ovf_cnt, ovf, E, nbkt);
    // p2 (buckets -> spair/counts) || k2 gemm, fused
    p2k2_fused<<<nbkt + gemmBlocks, 256, 0, stream>>>(
        binctr, bucket, counts, spair, ovf_cnt, ovf, U, Wtg, wb, out, N,
        nbkt, 0);
    // k3: accumulate
    k3_accumulate<<<(N + 3) / 4, 256, 0, stream>>>(
        counts, spair, wb, U, ovf_cnt, ovf, out, N);
  } else {
    // Fallback: transpose only, gemm w/ residual copy, atomic scatter.
    p1_bucket<<<1, 256, 0, stream>>>(W, Wtg, rows, cols, vals, (int*)Wtg,
                                     (int2*)Wtg, (int*)Wtg, (int4*)Wtg, 0, 0);
    p2k2_fused<<<gemmBlocks, 256, 0, stream>>>(
        (const int*)Wtg, (const int2*)Wtg, (int*)Wtg, (int2*)Wtg, (int*)Wtg,
        (int4*)Wtg, U, Wtg, wb, out, N, 0, 1);
    const long long total = (long long)E * 64;
    scatter_kernel<<<(int)((total + 255) / 256), 256, 0, stream>>>(
        rows, cols, vals, wb, out, E);
  }
}

// Round 3
// 149.746 us; speedup vs baseline: 2.9445x; 1.0810x over previous
//
#include <hip/hip_runtime.h>

#define DD 128         // EMBED_DIM
#define CAP 32         // (fallback kernels only)
#define OVF_MAX 4096   // overflow list capacity (int4 entries)
#define EPB 2048       // edges per scatter chunk
#define BSH 6          // bucket = row >> 6 (64 rows/bucket)
#define NB2 800        // max buckets (ceil(50000/64)=782)
#define BC2 1408       // bucket capacity: lambda=1023, sigma=32 -> +12 sigma
#define WTS 136

typedef __attribute__((ext_vector_type(8))) short short8;           // 8 bf16
typedef __attribute__((ext_vector_type(8))) unsigned short u16x8;   // 8 bf16
typedef __attribute__((ext_vector_type(4))) float f32x4;            // MFMA C/D

static __device__ __forceinline__ unsigned pack_bf16_2(float lo, float hi) {
  return __builtin_amdgcn_perm(__float_as_uint(hi) + 0x8000u,
                               __float_as_uint(lo) + 0x8000u, 0x07060302u);
}
static __device__ __forceinline__ unsigned short f2bf(float f) {
  return (unsigned short)((__float_as_uint(f) + 0x8000u) >> 16);
}
static __device__ __forceinline__ float bf2f(unsigned short h) {
  return __uint_as_float((unsigned)h << 16);
}

// ---------------------------------------------------------------------------
// Kernel A: blocks [0,nchunks) bucket-scatter edges into 64-row buckets
// (contiguous reserved runs -> merged line writebacks). Blocks [nchunks,..)
// MFMA GEMM with per-block W-transpose in LDS (independent of scatter).
// ---------------------------------------------------------------------------
__global__ __launch_bounds__(256) void kA_scatter_gemm(
    const float* __restrict__ U, const float* __restrict__ W,
    const int* __restrict__ rows, const int* __restrict__ cols,
    const float* __restrict__ vals, int* __restrict__ binctr,
    int2* __restrict__ bucket, int* __restrict__ ovf_cnt,
    int4* __restrict__ ovf, unsigned short* __restrict__ wb,
    int N, int E, int nchunks, int nbkt) {
  __shared__ union {
    struct {
      int lrow[EPB];   // 8 KB
      int hist[NB2];   // 3.2 KB
      int gbase[NB2];
      int lcur[NB2];
    } p1;              // 17.6 KB
    unsigned short Wt[DD][WTS];  // 34.8 KB
  } sm;
  const int t = threadIdx.x;

  if ((int)blockIdx.x < nchunks) {
    // ---- bucket scatter for one 2048-edge chunk ----
    const int c0 = blockIdx.x * EPB;
    const int n = min(EPB, E - c0);

    for (int j = t; j < nbkt; j += 256) { sm.p1.hist[j] = 0; sm.p1.lcur[j] = 0; }
    __syncthreads();

    // Pass A: stage rows, histogram by bucket.
    for (int i = t; i < n; i += 256) {
      const int r = rows[c0 + i];
      sm.p1.lrow[i] = r;
      atomicAdd(&sm.p1.hist[r >> BSH], 1);
    }
    __syncthreads();

    // Reserve contiguous runs in each bucket.
    for (int j = t; j < nbkt; j += 256)
      if (sm.p1.hist[j] > 0)
        sm.p1.gbase[j] = atomicAdd(&binctr[j], sm.p1.hist[j]);
    __syncthreads();

    // Pass B: place edges into runs (cols/vals re-read coalesced, L2-hot).
    for (int i = t; i < n; i += 256) {
      const int r = sm.p1.lrow[i];
      const int b = r >> BSH;
      const int lpos = atomicAdd(&sm.p1.lcur[b], 1);
      const int idx = sm.p1.gbase[b] + lpos;
      const int col = cols[c0 + i];
      const float v = vals[c0 + i];
      if (idx < BC2) {
        // pack: bits[27:22] = row&63, bits[21:0] = col (col < 4M)
        bucket[(size_t)b * BC2 + idx] =
            make_int2(((r & 63) << 22) | col, __float_as_int(v));
      } else {
        const int o = atomicAdd(ovf_cnt, 1);
        if (o < OVF_MAX) ovf[o] = make_int4(r, col, __float_as_int(v), 0);
      }
    }
    return;
  }

  // ---- GEMM: weighted(bf16) = U @ W, 128 rows/block, 4 waves x 32 rows ----
  const int gb = blockIdx.x - nchunks;
  {
    // Build Wt[n][k] = bf16(W[k][n]) in LDS directly from W (L2-broadcast).
    const int k0 = (t >> 4) * 8;
    const int n0 = (t & 15) * 8;
    float v[8][8];
#pragma unroll
    for (int kk = 0; kk < 8; ++kk) {
      float4 a = *(const float4*)(W + (k0 + kk) * DD + n0);
      float4 b = *(const float4*)(W + (k0 + kk) * DD + n0 + 4);
      v[kk][0] = a.x; v[kk][1] = a.y; v[kk][2] = a.z; v[kk][3] = a.w;
      v[kk][4] = b.x; v[kk][5] = b.y; v[kk][6] = b.z; v[kk][7] = b.w;
    }
#pragma unroll
    for (int nn = 0; nn < 8; ++nn) {
      uint4 d;
      d.x = pack_bf16_2(v[0][nn], v[1][nn]);
      d.y = pack_bf16_2(v[2][nn], v[3][nn]);
      d.z = pack_bf16_2(v[4][nn], v[5][nn]);
      d.w = pack_bf16_2(v[6][nn], v[7][nn]);
      *(uint4*)(&sm.Wt[n0 + nn][k0]) = d;
    }
  }
  __syncthreads();

  const int blk_row0 = gb * 128;
  const int w = t >> 6;
  const int lane = t & 63;
  const int m = lane & 15;
  const int quad = lane >> 4;
  const int row_base = blk_row0 + w * 32;

  short8 afrag[2][4];
#pragma unroll
  for (int s = 0; s < 2; ++s) {
    const int r = min(row_base + s * 16 + m, N - 1);
    const float* up = U + (size_t)r * DD + quad * 8;
#pragma unroll
    for (int c = 0; c < 4; ++c) {
      float4 x = *(const float4*)(up + c * 32);
      float4 y = *(const float4*)(up + c * 32 + 4);
      union { unsigned u[4]; short8 v; } fr;
      fr.u[0] = pack_bf16_2(x.x, x.y);
      fr.u[1] = pack_bf16_2(x.z, x.w);
      fr.u[2] = pack_bf16_2(y.x, y.y);
      fr.u[3] = pack_bf16_2(y.z, y.w);
      afrag[s][c] = fr.v;
    }
  }

  f32x4 acc[2][8];
#pragma unroll
  for (int s = 0; s < 2; ++s)
#pragma unroll
    for (int ct = 0; ct < 8; ++ct) acc[s][ct] = (f32x4){0.f, 0.f, 0.f, 0.f};

#pragma unroll
  for (int c = 0; c < 4; ++c) {
#pragma unroll
    for (int ct = 0; ct < 8; ++ct) {
      short8 bfrag = *(const short8*)&sm.Wt[ct * 16 + m][c * 32 + quad * 8];
      acc[0][ct] = __builtin_amdgcn_mfma_f32_16x16x32_bf16(
          afrag[0][c], bfrag, acc[0][ct], 0, 0, 0);
      acc[1][ct] = __builtin_amdgcn_mfma_f32_16x16x32_bf16(
          afrag[1][c], bfrag, acc[1][ct], 0, 0, 0);
    }
  }

  // Epilogue: C/D layout col=lane&15, row=quad*4+reg  [measured m89/m91].
#pragma unroll
  for (int s = 0; s < 2; ++s) {
    const int rb = row_base + s * 16 + quad * 4;
#pragma unroll
    for (int ct = 0; ct < 8; ++ct) {
#pragma unroll
      for (int reg = 0; reg < 4; ++reg) {
        const int r = rb + reg;
        if (r < N) wb[(size_t)r * DD + ct * 16 + m] = f2bf(acc[s][ct][reg]);
      }
    }
  }
}

// ---------------------------------------------------------------------------
// Kernel B: one block per 64-row bucket. Stage bucket edge list in LDS,
// counting-sort by row (64 LDS counters + serial prefix), then per-row
// wide-gather accumulate: lane group g=lane>>4 owns an edge, slot sl=lane&15
// owns 8 dims (16 B/lane -> 1 KB/wave/instr). Register accum, shfl reduce,
// residual add, store. No spair/counts global round-trip, no CAP clamp.
// ---------------------------------------------------------------------------
__global__ __launch_bounds__(256) void kB_sort_accumulate(
    const int* __restrict__ binctr, const int2* __restrict__ bucket,
    const unsigned short* __restrict__ wb, const float* __restrict__ U,
    const int* __restrict__ ovf_cnt, const int4* __restrict__ ovf,
    float* __restrict__ out, int N) {
  __shared__ int2 elist[BC2];   // 11.3 KB staged raw edges
  __shared__ int2 slist[BC2];   // 11.3 KB row-sorted (col,val)
  __shared__ int scnt[64];
  __shared__ int sbase[64];
  __shared__ int scur[64];

  const int t = threadIdx.x;
  const int b = blockIdx.x;
  const int base = b << BSH;
  const int n = min(binctr[b], BC2);

  if (t < 64) scnt[t] = 0;
  __syncthreads();

  for (int i = t; i < n; i += 256) {
    const int2 e = bucket[(size_t)b * BC2 + i];
    elist[i] = e;
    atomicAdd(&scnt[(unsigned)e.x >> 22], 1);
  }
  __syncthreads();

  if (t == 0) {
    int s = 0;
#pragma unroll 1
    for (int j = 0; j < 64; ++j) {
      sbase[j] = s;
      scur[j] = s;
      s += scnt[j];
    }
  }
  __syncthreads();

  for (int i = t; i < n; i += 256) {
    const int2 e = elist[i];
    const int pos = atomicAdd(&scur[(unsigned)e.x >> 22], 1);
    slist[pos] = make_int2(e.x & 0x3FFFFF, e.y);  // (col, val)
  }
  __syncthreads();

  const int lane = t & 63;
  const int w = t >> 6;
  const int g = lane >> 4;    // edge subgroup 0..3
  const int sl = lane & 15;   // dim slot: dims [8*sl .. 8*sl+7]
  const u16x8* __restrict__ WB8 = (const u16x8*)wb;  // row = 16 x u16x8
  const int nov = min(*ovf_cnt, OVF_MAX);  // wave-uniform broadcast load

  for (int rl = w; rl < 64; rl += 4) {
    const int r = base + rl;
    if (r >= N) break;
    const int cnt = scnt[rl];
    const int st = sbase[rl];

    float acc[8];
#pragma unroll
    for (int d = 0; d < 8; ++d) acc[d] = 0.f;

    int i = 0;
    // main: 16 edges / iter, 4 wide gathers in flight
    for (; i + 16 <= cnt; i += 16) {
      const int2 p0 = slist[st + i + g];
      const int2 p1 = slist[st + i + 4 + g];
      const int2 p2 = slist[st + i + 8 + g];
      const int2 p3 = slist[st + i + 12 + g];
      const u16x8 a0 = WB8[(size_t)p0.x * 16 + sl];
      const u16x8 a1 = WB8[(size_t)p1.x * 16 + sl];
      const u16x8 a2 = WB8[(size_t)p2.x * 16 + sl];
      const u16x8 a3 = WB8[(size_t)p3.x * 16 + sl];
      const float v0 = __int_as_float(p0.y);
      const float v1 = __int_as_float(p1.y);
      const float v2 = __int_as_float(p2.y);
      const float v3 = __int_as_float(p3.y);
#pragma unroll
      for (int d = 0; d < 8; ++d) {
        acc[d] = fmaf(v0, bf2f((unsigned short)a0[d]), acc[d]);
        acc[d] = fmaf(v1, bf2f((unsigned short)a1[d]), acc[d]);
        acc[d] = fmaf(v2, bf2f((unsigned short)a2[d]), acc[d]);
        acc[d] = fmaf(v3, bf2f((unsigned short)a3[d]), acc[d]);
      }
    }

    const int rem = cnt - i;  // 0..15
    if (rem > 8) {
      const int e0 = i + g, e1 = i + 4 + g, e2 = i + 8 + g, e3 = i + 12 + g;
      const int2 p0 = slist[st + min(e0, cnt - 1)];
      const int2 p1 = slist[st + min(e1, cnt - 1)];
      const int2 p2 = slist[st + min(e2, cnt - 1)];
      const int2 p3 = slist[st + min(e3, cnt - 1)];
      const u16x8 a0 = WB8[(size_t)p0.x * 16 + sl];
      const u16x8 a1 = WB8[(size_t)p1.x * 16 + sl];
      const u16x8 a2 = WB8[(size_t)p2.x * 16 + sl];
      const u16x8 a3 = WB8[(size_t)p3.x * 16 + sl];
      const float v0 = (e0 < cnt) ? __int_as_float(p0.y) : 0.f;
      const float v1 = (e1 < cnt) ? __int_as_float(p1.y) : 0.f;
      const float v2 = (e2 < cnt) ? __int_as_float(p2.y) : 0.f;
      const float v3 = (e3 < cnt) ? __int_as_float(p3.y) : 0.f;
#pragma unroll
      for (int d = 0; d < 8; ++d) {
        acc[d] = fmaf(v0, bf2f((unsigned short)a0[d]), acc[d]);
        acc[d] = fmaf(v1, bf2f((unsigned short)a1[d]), acc[d]);
        acc[d] = fmaf(v2, bf2f((unsigned short)a2[d]), acc[d]);
        acc[d] = fmaf(v3, bf2f((unsigned short)a3[d]), acc[d]);
      }
    } else if (rem > 0) {
      const int e0 = i + g, e1 = i + 4 + g;
      const int2 p0 = slist[st + min(e0, cnt - 1)];
      const int2 p1 = slist[st + min(e1, cnt - 1)];
      const u16x8 a0 = WB8[(size_t)p0.x * 16 + sl];
      const u16x8 a1 = WB8[(size_t)p1.x * 16 + sl];
      const float v0 = (e0 < cnt) ? __int_as_float(p0.y) : 0.f;
      const float v1 = (e1 < cnt) ? __int_as_float(p1.y) : 0.f;
#pragma unroll
      for (int d = 0; d < 8; ++d) {
        acc[d] = fmaf(v0, bf2f((unsigned short)a0[d]), acc[d]);
        acc[d] = fmaf(v1, bf2f((unsigned short)a1[d]), acc[d]);
      }
    }

    // reduce the 4 edge-subgroups: lanes {sl, sl+16, sl+32, sl+48} -> sl
#pragma unroll
    for (int d = 0; d < 8; ++d) {
      acc[d] += __shfl_xor(acc[d], 16, 64);
      acc[d] += __shfl_xor(acc[d], 32, 64);
    }

    // overflow entries (normally empty)
    if (nov > 0 && lane < 16) {
      for (int o = 0; o < nov; ++o) {
        const int4 e = ovf[o];
        if (e.x == r) {
          const float v = __int_as_float(e.z);
          const u16x8 a = WB8[(size_t)e.y * 16 + sl];
#pragma unroll
          for (int d = 0; d < 8; ++d)
            acc[d] = fmaf(v, bf2f((unsigned short)a[d]), acc[d]);
        }
      }
    }

    // residual add + store (quarter-wave covers the full 512 B row)
    if (lane < 16) {
      const float* up = U + (size_t)r * DD + sl * 8;
      const float4 u0 = *(const float4*)up;
      const float4 u1 = *(const float4*)(up + 4);
      float4 o0, o1;
      o0.x = acc[0] + u0.x; o0.y = acc[1] + u0.y;
      o0.z = acc[2] + u0.z; o0.w = acc[3] + u0.w;
      o1.x = acc[4] + u1.x; o1.y = acc[5] + u1.y;
      o1.z = acc[6] + u1.z; o1.w = acc[7] + u1.w;
      float* op = out + (size_t)r * DD + sl * 8;
      *(float4*)op = o0;
      *(float4*)(op + 4) = o1;
    }
  }
}

// ===========================================================================
// Fallback path (ws too small): transpose + gemm(copy residual) + atomics.
// ===========================================================================
__global__ __launch_bounds__(256) void p1_bucket(
    const float* __restrict__ W, unsigned short* __restrict__ Wtg,
    int E) {
  const int t = threadIdx.x;
  const int k0 = (t >> 4) * 8;
  const int n0 = (t & 15) * 8;
  float v[8][8];
#pragma unroll
  for (int kk = 0; kk < 8; ++kk) {
    float4 a = *(const float4*)(W + (k0 + kk) * DD + n0);
    float4 b = *(const float4*)(W + (k0 + kk) * DD + n0 + 4);
    v[kk][0] = a.x; v[kk][1] = a.y; v[kk][2] = a.z; v[kk][3] = a.w;
    v[kk][4] = b.x; v[kk][5] = b.y; v[kk][6] = b.z; v[kk][7] = b.w;
  }
#pragma unroll
  for (int nn = 0; nn < 8; ++nn) {
    uint4 d;
    d.x = pack_bf16_2(v[0][nn], v[1][nn]);
    d.y = pack_bf16_2(v[2][nn], v[3][nn]);
    d.z = pack_bf16_2(v[4][nn], v[5][nn]);
    d.w = pack_bf16_2(v[6][nn], v[7][nn]);
    *(uint4*)(Wtg + (size_t)(n0 + nn) * DD + k0) = d;
  }
}

__global__ __launch_bounds__(256) void k2_gemm_copy(
    const float* __restrict__ U, const unsigned short* __restrict__ Wtg,
    unsigned short* __restrict__ wb, float* __restrict__ out, int N) {
  __shared__ unsigned short Wt[DD][WTS];
  const int t = threadIdx.x;
  const int gb = blockIdx.x;
#pragma unroll
  for (int i = 0; i < 8; ++i) {
    const int s = t + 256 * i;
    const int nn = s >> 4;
    const int k0 = (s & 15) * 8;
    uint4 d = *(const uint4*)(Wtg + (size_t)nn * DD + k0);
    *(uint4*)(&Wt[nn][k0]) = d;
  }
  const int blk_row0 = gb * 128;
  {
    const int nrow = min(128, N - blk_row0);
    const float4* U4 = (const float4*)(U + (size_t)blk_row0 * DD);
    float4* O4 = (float4*)(out + (size_t)blk_row0 * DD);
    for (int i = t; i < nrow * 32; i += 256) O4[i] = U4[i];
  }
  __syncthreads();

  const int w = t >> 6;
  const int lane = t & 63;
  const int m = lane & 15;
  const int quad = lane >> 4;
  const int row_base = blk_row0 + w * 32;

  short8 afrag[2][4];
#pragma unroll
  for (int s = 0; s < 2; ++s) {
    const int r = min(row_base + s * 16 + m, N - 1);
    const float* up = U + (size_t)r * DD + quad * 8;
#pragma unroll
    for (int c = 0; c < 4; ++c) {
      float4 x = *(const float4*)(up + c * 32);
      float4 y = *(const float4*)(up + c * 32 + 4);
      union { unsigned u[4]; short8 v; } fr;
      fr.u[0] = pack_bf16_2(x.x, x.y);
      fr.u[1] = pack_bf16_2(x.z, x.w);
      fr.u[2] = pack_bf16_2(y.x, y.y);
      fr.u[3] = pack_bf16_2(y.z, y.w);
      afrag[s][c] = fr.v;
    }
  }

  f32x4 acc[2][8];
#pragma unroll
  for (int s = 0; s < 2; ++s)
#pragma unroll
    for (int ct = 0; ct < 8; ++ct) acc[s][ct] = (f32x4){0.f, 0.f, 0.f, 0.f};

#pragma unroll
  for (int c = 0; c < 4; ++c) {
#pragma unroll
    for (int ct = 0; ct < 8; ++ct) {
      short8 bfrag = *(const short8*)&Wt[ct * 16 + m][c * 32 + quad * 8];
      acc[0][ct] = __builtin_amdgcn_mfma_f32_16x16x32_bf16(
          afrag[0][c], bfrag, acc[0][ct], 0, 0, 0);
      acc[1][ct] = __builtin_amdgcn_mfma_f32_16x16x32_bf16(
          afrag[1][c], bfrag, acc[1][ct], 0, 0, 0);
    }
  }

#pragma unroll
  for (int s = 0; s < 2; ++s) {
    const int rb = row_base + s * 16 + quad * 4;
#pragma unroll
    for (int ct = 0; ct < 8; ++ct) {
#pragma unroll
      for (int reg = 0; reg < 4; ++reg) {
        const int r = rb + reg;
        if (r < N) wb[(size_t)r * DD + ct * 16 + m] = f2bf(acc[s][ct][reg]);
      }
    }
  }
}

__global__ __launch_bounds__(256) void scatter_kernel(
    const int* __restrict__ rows, const int* __restrict__ cols,
    const float* __restrict__ vals, const unsigned short* __restrict__ wb,
    float* __restrict__ out, int E) {
  const int tid = blockIdx.x * 256 + threadIdx.x;
  const int e = tid >> 6;
  if (e >= E) return;
  const int lane = tid & 63;

  const int row = rows[e];
  const int col = cols[e];
  const float v = vals[e];

  const ushort2 w = ((const ushort2*)wb)[(size_t)col * 64 + lane];
  float* dst = out + (size_t)row * DD + lane * 2;
  unsafeAtomicAdd(dst, v * bf2f(w.x));
  unsafeAtomicAdd(dst + 1, v * bf2f(w.y));
}

static inline size_t align_up(size_t x, size_t a) { return (x + a - 1) & ~(a - 1); }

extern "C" void kernel_launch(void* const* d_in, const int* in_sizes, int n_in,
                              void* d_out, int out_size, void* d_ws, size_t ws_size,
                              hipStream_t stream) {
  const float* U = (const float*)d_in[0];     // [N, 128]
  const float* W = (const float*)d_in[1];     // [128, 128]
  const int* rows = (const int*)d_in[2];      // [E]
  const int* cols = (const int*)d_in[3];      // [E]
  const float* vals = (const float*)d_in[4];  // [E]
  float* out = (float*)d_out;                 // [N, 128]

  const int N = in_sizes[0] / DD;
  const int E = in_sizes[2];
  const int gemmBlocks = (N + 127) / 128;
  const int nchunks = (E + EPB - 1) / EPB;
  const int nbkt = (N + (1 << BSH) - 1) >> BSH;  // 782 for N=50000

  // Workspace layout (16 B aligned segments)
  char* ws = (char*)d_ws;
  size_t off = 0;
  unsigned short* wb = (unsigned short*)(ws + off);
  off = align_up(off + (size_t)N * DD * sizeof(unsigned short), 16);
  unsigned short* Wtg = (unsigned short*)(ws + off);  // fallback only
  off = align_up(off + (size_t)DD * DD * sizeof(unsigned short), 16);
  int* binctr = (int*)(ws + off);  // NB2 bins + ovf counter, zeroed together
  int* ovf_cnt = binctr + NB2;
  off = align_up(off + (NB2 + 4) * sizeof(int), 16);
  int4* ovf = (int4*)(ws + off);
  off = align_up(off + (size_t)OVF_MAX * sizeof(int4), 16);
  int2* bucket = (int2*)(ws + off);
  off = align_up(off + (size_t)nbkt * BC2 * sizeof(int2), 16);
  const bool fast_ok = (off <= ws_size) && (nbkt <= NB2);

  if (fast_ok) {
    hipMemsetAsync(binctr, 0, (NB2 + 1) * sizeof(int), stream);  // 3.2 KB
    // A: bucket scatter (blocks [0,nchunks)) || GEMM (blocks [nchunks,..))
    kA_scatter_gemm<<<nchunks + gemmBlocks, 256, 0, stream>>>(
        U, W, rows, cols, vals, binctr, bucket, ovf_cnt, ovf, wb, N, E,
        nchunks, nbkt);
    // B: per-bucket LDS counting sort + wide-gather accumulate
    kB_sort_accumulate<<<nbkt, 256, 0, stream>>>(
        binctr, bucket, wb, U, ovf_cnt, ovf, out, N);
  } else {
    // Fallback: transpose, gemm w/ residual copy, atomic scatter.
    p1_bucket<<<1, 256, 0, stream>>>(W, Wtg, E);
    k2_gemm_copy<<<gemmBlocks, 256, 0, stream>>>(U, Wtg, wb, out, N);
    const long long total = (long long)E * 64;
    scatter_kernel<<<(int)((total + 255) / 256), 256, 0, stream>>>(
        rows, cols, vals, wb, out, E);
  }
}